// Round 6
// baseline (237.230 us; speedup 1.0000x reference)
//
#include <hip/hip_runtime.h>
#include <hip/hip_cooperative_groups.h>
#include <math.h>

namespace cg = cooperative_groups;

// Problem constants
#define BATCH 2
#define NTOK  2048
#define FIN   256
#define HEADS 8
#define FOUT  32
#define BH    (BATCH*HEADS)    // 16
#define NCOL  (HEADS*FOUT)     // 256
#define ROWS  (BATCH*NTOK)     // 4096

typedef _Float16 f16;
typedef _Float16 f16x8 __attribute__((ext_vector_type(8)));
typedef float    f32x4 __attribute__((ext_vector_type(4)));

// ---------------------------------------------------------------------------
// Workspace layout (float offsets). V1/P2V fg-plane-major [bh][fg][2049][4].
// partial ranks alias V1 (P2 writes partial -> P3 reads -> P4 overwrites V1;
// grid.sync() between phases makes the aliasing safe).
// ---------------------------------------------------------------------------
static const size_t OFF_E1   = 1048576;                 // e1  [16][2048]
static const size_t OFF_E2   = OFF_E1 + 32768;          // e2  [16][2048]
static const size_t OFF_SKEY = OFF_E2 + 32768;          // skey[16][2048]
static const size_t OFF_SIDX = OFF_SKEY + 32768;        // sidx[16][2048] int
static const size_t OFF_W1S  = OFF_SIDX + 32768;        // w1s [16][2048]
static const size_t OFF_W2S  = OFF_W1S + 32768;         // w2s [16][2048]
static const size_t OFF_S1   = OFF_W2S + 32768;         // S1  [16][2049]
static const size_t OFF_P2   = OFF_S1 + 32784;          // P2  [16][2049]
static const size_t OFF_V1   = OFF_P2 + 32784;          // V1  [16][8][2049][4]
static const size_t OFF_P2V  = OFF_V1 + 16u*2049u*32u;  // P2V [16][8][2049][4]
static const size_t OFF_PART = OFF_V1;                  // partial[8][16][2048] int (aliases V1)

// Monotone float->u32 bit map packed with (2047-j): one u64 compare gives the
// descending-with-index-tiebreak total order.
__device__ __forceinline__ unsigned long long sortkey(float f, int j) {
    unsigned int b = __float_as_uint(f);
    unsigned int u = (b & 0x80000000u) ? ~b : (b | 0x80000000u);
    return ((unsigned long long)u << 32) | (unsigned int)(NTOK - 1 - j);
}

// ---------------------------------------------------------------------------
// MEGA-KERNEL: all 5 phases in one cooperative launch.
// grid 256 blocks x 512 thr = 1 block/CU (always co-resident); 4 grid.sync()
// replace 4 dependent-dispatch drain gaps.
// ---------------------------------------------------------------------------
__global__ __launch_bounds__(512) void k_mega(const float* __restrict__ h,
                                              const float* __restrict__ W,
                                              const float* __restrict__ av,
                                              float* __restrict__ Wh,
                                              float* __restrict__ e1, float* __restrict__ e2,
                                              float* __restrict__ skey, int* __restrict__ sidx,
                                              float* __restrict__ w1s, float* __restrict__ w2s,
                                              float* __restrict__ S1, float* __restrict__ P2g,
                                              float* __restrict__ V1, float* __restrict__ P2V,
                                              int* __restrict__ partial,
                                              float* __restrict__ out) {
    cg::grid_group grid = cg::this_grid();
    __shared__ float skeys[NTOK];                       // P5 (8 KB)
    __shared__ alignas(16) unsigned long long ch[256];  // P2 (2 KB)
    __shared__ float4 wtot[8];                          // P4
    __shared__ float4 woff[8];                          // P4

    const int tid = threadIdx.x;
    const int bid = blockIdx.x;

    // =======================================================================
    // P1: Wh = h @ W via MFMA f16 hi/lo split (in-register), fused e1/e2.
    // Block = 16 rows x 256 cols; wave == head (16x32 = 2 MFMA col-tiles).
    // A row=lane&15, k=(lane>>4)*8+j; B col likewise from W[k][col];
    // C col=lane&15, row=(lane>>4)*4+g. h*2^4, W*2^12; epilogue *2^-16.
    // =======================================================================
    {
        const int hh   = tid >> 6;        // wave index == head
        const int lane = tid & 63;
        const int r    = lane & 15;
        const int q    = lane >> 4;
        const int row0 = bid * 16;
        const int colA = hh * 32;

        const float* pa = h + (size_t)(row0 + r) * FIN + q * 8;
        const float HS = 16.0f, WS = 4096.0f;

        f32x4 acc[2];
        acc[0] = (f32x4){0.f,0.f,0.f,0.f};
        acc[1] = (f32x4){0.f,0.f,0.f,0.f};

        for (int ks = 0; ks < 8; ++ks) {
            const int kb = ks * 32;
            const float4 a0 = *(const float4*)(pa + kb);
            const float4 a1 = *(const float4*)(pa + kb + 4);
            const float ax[8] = {a0.x,a0.y,a0.z,a0.w,a1.x,a1.y,a1.z,a1.w};
            f16x8 ahi, alo;
            #pragma unroll
            for (int j = 0; j < 8; ++j) {
                float xv = ax[j] * HS;
                f16 hv = (f16)xv;
                ahi[j] = hv; alo[j] = (f16)(xv - (float)hv);
            }
            f16x8 bhi[2], blo[2];
            #pragma unroll
            for (int t = 0; t < 2; ++t) {
                const float* pb = W + (size_t)(kb + q * 8) * NCOL + colA + t * 16 + r;
                #pragma unroll
                for (int j = 0; j < 8; ++j) {
                    float xv = pb[(size_t)j * NCOL] * WS;
                    f16 hv = (f16)xv;
                    bhi[t][j] = hv; blo[t][j] = (f16)(xv - (float)hv);
                }
            }
            #pragma unroll
            for (int t = 0; t < 2; ++t) {
                acc[t] = __builtin_amdgcn_mfma_f32_16x16x32_f16(ahi, bhi[t], acc[t], 0, 0, 0);
                acc[t] = __builtin_amdgcn_mfma_f32_16x16x32_f16(ahi, blo[t], acc[t], 0, 0, 0);
                acc[t] = __builtin_amdgcn_mfma_f32_16x16x32_f16(alo, bhi[t], acc[t], 0, 0, 0);
            }
        }

        const float SC = 1.0f / 65536.0f;   // undo 2^4 * 2^12
        acc[0] *= SC; acc[1] *= SC;

        #pragma unroll
        for (int t = 0; t < 2; ++t)
            #pragma unroll
            for (int g = 0; g < 4; ++g)
                Wh[(size_t)(row0 + q * 4 + g) * NCOL + colA + t * 16 + r] = acc[t][g];

        const float a10 = av[r], a11 = av[16 + r];
        const float a20 = av[32 + r], a21 = av[48 + r];
        float p1[4], p2[4];
        #pragma unroll
        for (int g = 0; g < 4; ++g) {
            p1[g] = acc[0][g] * a10 + acc[1][g] * a11;
            p2[g] = acc[0][g] * a20 + acc[1][g] * a21;
        }
        #pragma unroll
        for (int m = 1; m < 16; m <<= 1)
            #pragma unroll
            for (int g = 0; g < 4; ++g) {
                p1[g] += __shfl_xor(p1[g], m, 64);
                p2[g] += __shfl_xor(p2[g], m, 64);
            }
        if (r == 0) {
            #pragma unroll
            for (int g = 0; g < 4; ++g) {
                const int row = row0 + q * 4 + g;
                const int b   = row >> 11;
                const int n   = row & (NTOK - 1);
                e1[(b * HEADS + hh) * NTOK + n] = p1[g];
                e2[(b * HEADS + hh) * NTOK + n] = p2[g];
            }
        }
    }
    grid.sync();

    // =======================================================================
    // P2: partial descending ranks, 4-j amortized. Task (bh,kt,jh) = bid;
    // lower 256 threads stage the 256-key chunk and rank 4 j's each.
    // Per-CU LDS-instr load identical to the standalone version.
    // =======================================================================
    {
        const int bh = bid & 15;
        const int kt = (bid >> 4) & 7;
        const int jh = bid >> 7;
        const int kbase = kt * 256;
        if (tid < 256)
            ch[tid] = sortkey(e2[bh * NTOK + kbase + tid], kbase + tid);
        __syncthreads();
        if (tid < 256) {
            const int j0 = jh * 1024 + tid * 4;
            const float4 mv = *(const float4*)(e2 + bh * NTOK + j0);
            const unsigned long long my0 = sortkey(mv.x, j0);
            const unsigned long long my1 = sortkey(mv.y, j0 + 1);
            const unsigned long long my2 = sortkey(mv.z, j0 + 2);
            const unsigned long long my3 = sortkey(mv.w, j0 + 3);
            int r0 = 0, r1 = 0, r2 = 0, r3 = 0;
            const ulonglong2* c2 = (const ulonglong2*)ch;
            #pragma unroll 8
            for (int qq = 0; qq < 128; ++qq) {
                ulonglong2 v = c2[qq];
                r0 += (v.x > my0) + (v.y > my0);
                r1 += (v.x > my1) + (v.y > my1);
                r2 += (v.x > my2) + (v.y > my2);
                r3 += (v.x > my3) + (v.y > my3);
            }
            *(int4*)(partial + (size_t)(kt * BH + bh) * NTOK + j0) = make_int4(r0, r1, r2, r3);
        }
    }
    grid.sync();

    // =======================================================================
    // P3: sum 8 partials -> rank; scatter key/idx and exp weights.
    // 128 active blocks, lower 256 threads.
    // =======================================================================
    if (bid < 128 && tid < 256) {
        const int bh = bid & 15;
        const int jt = bid >> 4;
        const int j  = jt * 256 + tid;
        int rank = 0;
        #pragma unroll
        for (int kt = 0; kt < 8; ++kt)
            rank += partial[(size_t)(kt * BH + bh) * NTOK + j];
        const float my = e2[bh * NTOK + j];
        skey[bh * NTOK + rank] = my;
        sidx[bh * NTOK + rank] = j;
        w1s[bh * NTOK + rank]  = expf(my);
        w2s[bh * NTOK + rank]  = expf(0.01f * my);
    }
    grid.sync();

    // =======================================================================
    // P4: z-fused scans, 144 active blocks x 512 thr, 4 elems/thread.
    // Gather Wh once; scan both w1 (->V1/S1) and w2 (->P2V/P2) from regs.
    // Writes exclusive form dst[k]=incl[k-1], dst[0]=0, dst[2048]=total.
    // =======================================================================
    if (bid < 144) {
        const int fg = bid >> 4;       // 0..8
        const int bh = bid & 15;
        const int b  = bh >> 3;
        const int hh = bh & 7;
        const int lane = tid & 63;
        const int wv   = tid >> 6;     // 8 waves
        const int j0   = 4 * tid;

        float w1v[4], w2v[4];
        float4 g[4];
        #pragma unroll
        for (int i = 0; i < 4; ++i) {
            w1v[i] = w1s[bh * NTOK + j0 + i];
            w2v[i] = w2s[bh * NTOK + j0 + i];
        }
        if (fg < 8) {
            #pragma unroll
            for (int i = 0; i < 4; ++i) {
                const int sj = sidx[bh * NTOK + j0 + i];
                g[i] = *(const float4*)(Wh + (size_t)(b * NTOK + sj) * NCOL + hh * FOUT + fg * 4);
            }
        } else {
            #pragma unroll
            for (int i = 0; i < 4; ++i) g[i] = make_float4(1.f, 0.f, 0.f, 0.f);
        }

        #pragma unroll 1
        for (int z = 0; z < 2; ++z) {
            float4 v[4];
            #pragma unroll
            for (int i = 0; i < 4; ++i) {
                const float w = z ? w2v[i] : w1v[i];
                v[i] = make_float4(w * g[i].x, w * g[i].y, w * g[i].z, w * g[i].w);
            }
            float4 s = make_float4(v[0].x + v[1].x + v[2].x + v[3].x,
                                   v[0].y + v[1].y + v[2].y + v[3].y,
                                   v[0].z + v[1].z + v[2].z + v[3].z,
                                   v[0].w + v[1].w + v[2].w + v[3].w);
            const float4 quad = s;
            #pragma unroll
            for (int d = 1; d < 64; d <<= 1) {
                float ux = __shfl_up(s.x, (unsigned)d, 64);
                float uy = __shfl_up(s.y, (unsigned)d, 64);
                float uz = __shfl_up(s.z, (unsigned)d, 64);
                float uw = __shfl_up(s.w, (unsigned)d, 64);
                if (lane >= d) { s.x += ux; s.y += uy; s.z += uz; s.w += uw; }
            }
            float4 excl = make_float4(s.x - quad.x, s.y - quad.y, s.z - quad.z, s.w - quad.w);
            if (lane == 63) wtot[wv] = s;
            __syncthreads();
            if (tid < 8) {
                float4 ws = wtot[tid];
                float4 inc = ws;
                #pragma unroll
                for (int d = 1; d < 8; d <<= 1) {
                    float ux = __shfl_up(inc.x, (unsigned)d, 8);
                    float uy = __shfl_up(inc.y, (unsigned)d, 8);
                    float uz = __shfl_up(inc.z, (unsigned)d, 8);
                    float uw = __shfl_up(inc.w, (unsigned)d, 8);
                    if ((tid & 7) >= d) { inc.x += ux; inc.y += uy; inc.z += uz; inc.w += uw; }
                }
                woff[tid] = make_float4(inc.x - ws.x, inc.y - ws.y, inc.z - ws.z, inc.w - ws.w);
            }
            __syncthreads();

            float4 base = woff[wv];
            float4 run = make_float4(base.x + excl.x, base.y + excl.y,
                                     base.z + excl.z, base.w + excl.w);
            float4 io[4];
            #pragma unroll
            for (int i = 0; i < 4; ++i) {
                run = make_float4(run.x + v[i].x, run.y + v[i].y,
                                  run.z + v[i].z, run.w + v[i].w);
                io[i] = run;
            }

            if (fg < 8) {
                float* dst = z ? P2V : V1;
                float* plane = dst + ((size_t)bh * 8 + fg) * (2049u * 4u);
                #pragma unroll
                for (int i = 0; i < 4; ++i)
                    *(float4*)(plane + (size_t)(j0 + 1 + i) * 4) = io[i];
                if (tid == 0)
                    *(float4*)plane = make_float4(0.f, 0.f, 0.f, 0.f);
            } else {
                float* dst = z ? P2g : S1;
                #pragma unroll
                for (int i = 0; i < 4; ++i)
                    dst[bh * 2049 + j0 + 1 + i] = io[i].x;
                if (tid == 0) dst[bh * 2049] = 0.f;
            }
            __syncthreads();   // protect wtot/woff reuse by the next z pass
        }
    }
    grid.sync();

    // =======================================================================
    // P5: per (b,h,i): binary-search k_i, combine prefix sums, write output.
    // Block = one bh x 4 itiles; keys staged once; 2 x 256-thr units x 2 seq.
    // =======================================================================
    {
        const int bh     = bid & 15;
        const int itbase = (bid >> 4) * 4;   // 0,4,...,60
        const int b      = bh >> 3;
        const int hh     = bh & 7;
        #pragma unroll
        for (int q = 0; q < 4; ++q)
            skeys[q * 512 + tid] = skey[bh * NTOK + q * 512 + tid];
        __syncthreads();

        const int unit = tid >> 8;     // 0..1
        const int ut   = tid & 255;
        #pragma unroll
        for (int s = 0; s < 2; ++s) {
            const int it = itbase + s * 2 + unit;
            const int i  = it * 32 + (ut >> 3);
            const int fg = ut & 7;
            const float e1v = e1[bh * NTOK + i];
            const float th  = -e1v;
            int lo = 0, hi = NTOK;
            while (lo < hi) {
                int mid = (lo + hi) >> 1;
                if (skeys[mid] > th) lo = mid + 1; else hi = mid;
            }
            const int k = lo;
            const float A = expf(e1v);
            const float C = expf(0.01f * e1v);
            const float s1  = S1[bh * 2049 + k];
            const float p2k = P2g[bh * 2049 + k];
            const float p2t = P2g[bh * 2049 + 2048];
            const float l   = A * s1 + C * (p2t - p2k);
            const float inv = 1.0f / l;
            const float* v1p  = V1  + ((size_t)bh * 8 + fg) * (2049u * 4u);
            const float* p2vp = P2V + ((size_t)bh * 8 + fg) * (2049u * 4u);
            float4 v1   = *(const float4*)(v1p  + (size_t)k * 4);
            float4 p2v  = *(const float4*)(p2vp + (size_t)k * 4);
            float4 p2vt = *(const float4*)(p2vp + (size_t)2048 * 4);
            float4 o;
            o.x = (A * v1.x + C * (p2vt.x - p2v.x)) * inv;
            o.y = (A * v1.y + C * (p2vt.y - p2v.y)) * inv;
            o.z = (A * v1.z + C * (p2vt.z - p2v.z)) * inv;
            o.w = (A * v1.w + C * (p2vt.w - p2v.w)) * inv;
            *(float4*)(out + (size_t)(b * NTOK + i) * NCOL + hh * FOUT + fg * 4) = o;
        }
    }
}

// ---------------------------------------------------------------------------
extern "C" void kernel_launch(void* const* d_in, const int* in_sizes, int n_in,
                              void* d_out, int out_size, void* d_ws, size_t ws_size,
                              hipStream_t stream) {
    const float* h = (const float*)d_in[0];
    // d_in[1] = adj — unused by the reference computation
    const float* W = (const float*)d_in[2];
    const float* a = (const float*)d_in[3];
    float* out = (float*)d_out;
    float* ws  = (float*)d_ws;

    float* Wh   = ws;
    float* e1   = ws + OFF_E1;
    float* e2   = ws + OFF_E2;
    float* skey = ws + OFF_SKEY;
    int*   sidx = (int*)(ws + OFF_SIDX);
    float* w1s  = ws + OFF_W1S;
    float* w2s  = ws + OFF_W2S;
    float* S1   = ws + OFF_S1;
    float* P2   = ws + OFF_P2;
    float* V1   = ws + OFF_V1;
    float* P2V  = ws + OFF_P2V;
    int*   part = (int*)(ws + OFF_PART);   // aliases V1 (safe: grid.sync-ordered)

    void* args[] = { (void*)&h, (void*)&W, (void*)&a, (void*)&Wh, (void*)&e1, (void*)&e2,
                     (void*)&skey, (void*)&sidx, (void*)&w1s, (void*)&w2s,
                     (void*)&S1, (void*)&P2, (void*)&V1, (void*)&P2V,
                     (void*)&part, (void*)&out };
    hipLaunchCooperativeKernel((const void*)k_mega, dim3(256), dim3(512),
                               args, 0, stream);
}

// Round 7
// 116.299 us; speedup vs baseline: 2.0398x; 2.0398x over previous
//
#include <hip/hip_runtime.h>
#include <math.h>

// Problem constants
#define BATCH 2
#define NTOK  2048
#define FIN   256
#define HEADS 8
#define FOUT  32
#define BH    (BATCH*HEADS)    // 16
#define NCOL  (HEADS*FOUT)     // 256
#define ROWS  (BATCH*NTOK)     // 4096

typedef _Float16 f16;
typedef _Float16 f16x8 __attribute__((ext_vector_type(8)));
typedef float    f32x4 __attribute__((ext_vector_type(4)));

// ---------------------------------------------------------------------------
// Workspace layout (float offsets).
// V1/P2V fg-plane-major [bh][fg][2049][4]. partial ranks alias V1 (rank8
// writes partial -> scatter reads -> vscan overwrites V1 later; strict
// stream order makes the aliasing safe). The fp32->f16 hi/lo split happens
// in-register inside k_mm (no staging buffers).
// ---------------------------------------------------------------------------
static const size_t OFF_E1   = 1048576;                 // e1  [16][2048]
static const size_t OFF_E2   = OFF_E1 + 32768;          // e2  [16][2048]
static const size_t OFF_SKEY = OFF_E2 + 32768;          // skey[16][2048]
static const size_t OFF_SIDX = OFF_SKEY + 32768;        // sidx[16][2048] int
static const size_t OFF_W1S  = OFF_SIDX + 32768;        // w1s [16][2048]
static const size_t OFF_W2S  = OFF_W1S + 32768;         // w2s [16][2048]
static const size_t OFF_S1   = OFF_W2S + 32768;         // S1  [16][2049]
static const size_t OFF_P2   = OFF_S1 + 32784;          // P2  [16][2049]
static const size_t OFF_V1   = OFF_P2 + 32784;          // V1  [16][8][2049][4]
static const size_t OFF_P2V  = OFF_V1 + 16u*2049u*32u;  // P2V [16][8][2049][4]
static const size_t OFF_PART = OFF_V1;                  // partial[8][16][2048] int (aliases V1)

// ---------------------------------------------------------------------------
// K1: Wh = h @ W via MFMA f16 hi/lo split (Ah*Bh + Ah*Bl + Al*Bh), with the
// fp32->f16 split done IN-REGISTER. grid 256 x 512 thr; block = 16 rows x
// 256 cols; wave == head (16x32 = 2 MFMA col-tiles). h*2^4, W*2^12 keeps lo
// residuals f16-normal; epilogue *2^-16. Frag layout (R4/R5-validated):
// A row=lane&15, k=(lane>>4)*8+j; B col likewise from W[k][col];
// C col=lane&15, row=(lane>>4)*4+g. Fused e1/e2 epilogue (16-lane reduce).
// [R6 lesson: do NOT fold phases into a cooperative kernel — grid.sync()
//  measured ~33 us each on this chip (k_mega 147us, VALUBusy 5.2%).]
// ---------------------------------------------------------------------------
__global__ __launch_bounds__(512) void k_mm(const float* __restrict__ h,
                                            const float* __restrict__ W,
                                            const float* __restrict__ av,
                                            float* __restrict__ Wh,
                                            float* __restrict__ e1, float* __restrict__ e2) {
    const int tid  = threadIdx.x;
    const int hh   = tid >> 6;        // wave index == head
    const int lane = tid & 63;
    const int r    = lane & 15;
    const int q    = lane >> 4;
    const int row0 = blockIdx.x * 16;
    const int colA = hh * 32;

    const float* pa = h + (size_t)(row0 + r) * FIN + q * 8;
    const float HS = 16.0f, WS = 4096.0f;

    f32x4 acc[2];
    acc[0] = (f32x4){0.f,0.f,0.f,0.f};
    acc[1] = (f32x4){0.f,0.f,0.f,0.f};

    for (int ks = 0; ks < 8; ++ks) {
        const int kb = ks * 32;
        // ---- A split in-register ----
        const float4 a0 = *(const float4*)(pa + kb);
        const float4 a1 = *(const float4*)(pa + kb + 4);
        const float ax[8] = {a0.x,a0.y,a0.z,a0.w,a1.x,a1.y,a1.z,a1.w};
        f16x8 ahi, alo;
        #pragma unroll
        for (int j = 0; j < 8; ++j) {
            float xv = ax[j] * HS;
            f16 hv = (f16)xv;
            ahi[j] = hv; alo[j] = (f16)(xv - (float)hv);
        }
        // ---- B split in-register, 2 col-tiles ----
        f16x8 bhi[2], blo[2];
        #pragma unroll
        for (int t = 0; t < 2; ++t) {
            const float* pb = W + (size_t)(kb + q * 8) * NCOL + colA + t * 16 + r;
            #pragma unroll
            for (int j = 0; j < 8; ++j) {
                float xv = pb[(size_t)j * NCOL] * WS;
                f16 hv = (f16)xv;
                bhi[t][j] = hv; blo[t][j] = (f16)(xv - (float)hv);
            }
        }
        #pragma unroll
        for (int t = 0; t < 2; ++t) {
            acc[t] = __builtin_amdgcn_mfma_f32_16x16x32_f16(ahi, bhi[t], acc[t], 0, 0, 0);
            acc[t] = __builtin_amdgcn_mfma_f32_16x16x32_f16(ahi, blo[t], acc[t], 0, 0, 0);
            acc[t] = __builtin_amdgcn_mfma_f32_16x16x32_f16(alo, bhi[t], acc[t], 0, 0, 0);
        }
    }

    const float SC = 1.0f / 65536.0f;   // undo 2^4 * 2^12
    acc[0] *= SC; acc[1] *= SC;

    // Wh write (fp32)
    #pragma unroll
    for (int t = 0; t < 2; ++t)
        #pragma unroll
        for (int g = 0; g < 4; ++g)
            Wh[(size_t)(row0 + q * 4 + g) * NCOL + colA + t * 16 + r] = acc[t][g];

    // fused e1/e2: wave == head; f = t*16 + r
    const float a10 = av[r], a11 = av[16 + r];
    const float a20 = av[32 + r], a21 = av[48 + r];
    float p1[4], p2[4];
    #pragma unroll
    for (int g = 0; g < 4; ++g) {
        p1[g] = acc[0][g] * a10 + acc[1][g] * a11;
        p2[g] = acc[0][g] * a20 + acc[1][g] * a21;
    }
    #pragma unroll
    for (int m = 1; m < 16; m <<= 1)
        #pragma unroll
        for (int g = 0; g < 4; ++g) {
            p1[g] += __shfl_xor(p1[g], m, 64);
            p2[g] += __shfl_xor(p2[g], m, 64);
        }
    if (r == 0) {
        #pragma unroll
        for (int g = 0; g < 4; ++g) {
            const int row = row0 + q * 4 + g;
            const int b   = row >> 11;
            const int n   = row & (NTOK - 1);
            e1[(b * HEADS + hh) * NTOK + n] = p1[g];
            e2[(b * HEADS + hh) * NTOK + n] = p2[g];
        }
    }
}

// ---------------------------------------------------------------------------
// Monotone float->u32 bit map packed with (2047-j): one u64 compare gives the
// descending-with-index-tiebreak total order.
// ---------------------------------------------------------------------------
__device__ __forceinline__ unsigned long long sortkey(float f, int j) {
    unsigned int b = __float_as_uint(f);
    unsigned int u = (b & 0x80000000u) ? ~b : (b | 0x80000000u);
    return ((unsigned long long)u << 32) | (unsigned int)(NTOK - 1 - j);
}

// ---------------------------------------------------------------------------
// K3a: partial descending ranks, 4-j amortized. grid (16 bh, 8 kt, 2 jh),
// block 256 -> 256 blocks (1/CU). Each thread ranks FOUR j's against the
// staged 256-key chunk: LDS-issue count per CU drops 4x vs the 1-j version,
// balanced against the u64-compare VALU stream.
// ---------------------------------------------------------------------------
__global__ __launch_bounds__(256) void k_rank8(const float* __restrict__ e2g,
                                               int* __restrict__ partial) {
    __shared__ alignas(16) unsigned long long ch[256];
    const int tid = threadIdx.x;
    const int bh  = blockIdx.x;
    const int kt  = blockIdx.y;
    const int jh  = blockIdx.z;
    const int kbase = kt * 256;
    ch[tid] = sortkey(e2g[bh * NTOK + kbase + tid], kbase + tid);
    __syncthreads();

    const int j0 = jh * 1024 + tid * 4;
    const float4 mv = *(const float4*)(e2g + bh * NTOK + j0);
    const unsigned long long my0 = sortkey(mv.x, j0);
    const unsigned long long my1 = sortkey(mv.y, j0 + 1);
    const unsigned long long my2 = sortkey(mv.z, j0 + 2);
    const unsigned long long my3 = sortkey(mv.w, j0 + 3);
    int r0 = 0, r1 = 0, r2 = 0, r3 = 0;
    const ulonglong2* c2 = (const ulonglong2*)ch;
    #pragma unroll 8
    for (int qq = 0; qq < 128; ++qq) {
        ulonglong2 v = c2[qq];
        r0 += (v.x > my0) + (v.y > my0);
        r1 += (v.x > my1) + (v.y > my1);
        r2 += (v.x > my2) + (v.y > my2);
        r3 += (v.x > my3) + (v.y > my3);
    }
    *(int4*)(partial + (size_t)(kt * BH + bh) * NTOK + j0) = make_int4(r0, r1, r2, r3);
}

// ---------------------------------------------------------------------------
// K3b: sum 8 partials -> rank; scatter key/idx and exp weights.
// grid (16,8), block 256.
// ---------------------------------------------------------------------------
__global__ __launch_bounds__(256) void k_scatter(const float* __restrict__ e2g,
                                                 const int* __restrict__ partial,
                                                 float* __restrict__ skey,
                                                 int* __restrict__ sidx,
                                                 float* __restrict__ w1s,
                                                 float* __restrict__ w2s) {
    const int tid = threadIdx.x;
    const int bh  = blockIdx.x;
    const int jt  = blockIdx.y;
    const int j   = jt * 256 + tid;
    int rank = 0;
    #pragma unroll
    for (int kt = 0; kt < 8; ++kt)
        rank += partial[(size_t)(kt * BH + bh) * NTOK + j];
    const float my = e2g[bh * NTOK + j];
    skey[bh * NTOK + rank] = my;
    sidx[bh * NTOK + rank] = j;
    w1s[bh * NTOK + rank]  = expf(my);
    w2s[bh * NTOK + rank]  = expf(0.01f * my);
}

// ---------------------------------------------------------------------------
// K4: work-efficient scans, z-FUSED. grid (9 fg, 16 bh), block 1024.
// The Wh gather (the expensive random part) happens ONCE; both z=0 (w1)
// and z=1 (w2) scans run from registers. 144 blocks (no 2-block/CU tail).
// fg==8 handled by the same float4 path via g=(1,0,0,0).
// Writes exclusive form dst[k]=incl[k-1], dst[0]=0, dst[2048]=total.
// ---------------------------------------------------------------------------
__global__ __launch_bounds__(1024) void k_vscan(const float* __restrict__ Wh,
                                                const int* __restrict__ sidx,
                                                const float* __restrict__ w1s,
                                                const float* __restrict__ w2s,
                                                float* __restrict__ V1,
                                                float* __restrict__ P2V,
                                                float* __restrict__ S1,
                                                float* __restrict__ P2) {
    __shared__ float4 wtot[16];
    __shared__ float4 woff[16];
    const int t    = threadIdx.x;
    const int lane = t & 63;
    const int wv   = t >> 6;
    const int fg   = blockIdx.x;
    const int bh   = blockIdx.y;
    const int b    = bh >> 3;
    const int hh   = bh & 7;
    const int j0   = 2 * t;

    const float w1_0 = w1s[bh * NTOK + j0], w1_1 = w1s[bh * NTOK + j0 + 1];
    const float w2_0 = w2s[bh * NTOK + j0], w2_1 = w2s[bh * NTOK + j0 + 1];
    float4 g0, g1;
    if (fg < 8) {
        const int sj0 = sidx[bh * NTOK + j0];
        const int sj1 = sidx[bh * NTOK + j0 + 1];
        g0 = *(const float4*)(Wh + (size_t)(b * NTOK + sj0) * NCOL + hh * FOUT + fg * 4);
        g1 = *(const float4*)(Wh + (size_t)(b * NTOK + sj1) * NCOL + hh * FOUT + fg * 4);
    } else {
        g0 = make_float4(1.f, 0.f, 0.f, 0.f);
        g1 = make_float4(1.f, 0.f, 0.f, 0.f);
    }

    #pragma unroll 1
    for (int z = 0; z < 2; ++z) {
        const float w0  = z ? w2_0 : w1_0;
        const float w1v = z ? w2_1 : w1_1;
        float4 v0 = make_float4(w0 * g0.x,  w0 * g0.y,  w0 * g0.z,  w0 * g0.w);
        float4 v1 = make_float4(w1v * g1.x, w1v * g1.y, w1v * g1.z, w1v * g1.w);

        // thread-local pair sum, then inclusive wave scan
        float4 s = make_float4(v0.x + v1.x, v0.y + v1.y, v0.z + v1.z, v0.w + v1.w);
        #pragma unroll
        for (int d = 1; d < 64; d <<= 1) {
            float ux = __shfl_up(s.x, (unsigned)d, 64);
            float uy = __shfl_up(s.y, (unsigned)d, 64);
            float uz = __shfl_up(s.z, (unsigned)d, 64);
            float uw = __shfl_up(s.w, (unsigned)d, 64);
            if (lane >= d) { s.x += ux; s.y += uy; s.z += uz; s.w += uw; }
        }
        float4 pair = make_float4(v0.x + v1.x, v0.y + v1.y, v0.z + v1.z, v0.w + v1.w);
        float4 excl = make_float4(s.x - pair.x, s.y - pair.y, s.z - pair.z, s.w - pair.w);
        if (lane == 63) wtot[wv] = s;
        __syncthreads();
        if (t < 16) {
            float4 ws = wtot[t];
            float4 inc = ws;
            #pragma unroll
            for (int d = 1; d < 16; d <<= 1) {
                float ux = __shfl_up(inc.x, (unsigned)d, 16);
                float uy = __shfl_up(inc.y, (unsigned)d, 16);
                float uz = __shfl_up(inc.z, (unsigned)d, 16);
                float uw = __shfl_up(inc.w, (unsigned)d, 16);
                if ((t & 15) >= d) { inc.x += ux; inc.y += uy; inc.z += uz; inc.w += uw; }
            }
            woff[t] = make_float4(inc.x - ws.x, inc.y - ws.y, inc.z - ws.z, inc.w - ws.w);
        }
        __syncthreads();

        float4 base = woff[wv];
        float4 i0 = make_float4(base.x + excl.x + v0.x, base.y + excl.y + v0.y,
                                base.z + excl.z + v0.z, base.w + excl.w + v0.w);
        float4 i1 = make_float4(i0.x + v1.x, i0.y + v1.y, i0.z + v1.z, i0.w + v1.w);

        if (fg < 8) {
            float* dst = z ? P2V : V1;
            float* plane = dst + ((size_t)bh * 8 + fg) * (2049u * 4u);
            *(float4*)(plane + (size_t)(j0 + 1) * 4) = i0;
            *(float4*)(plane + (size_t)(j0 + 2) * 4) = i1;
            if (t == 0)
                *(float4*)plane = make_float4(0.f, 0.f, 0.f, 0.f);
        } else {
            float* dst = z ? P2 : S1;
            dst[bh * 2049 + j0 + 1] = i0.x;
            dst[bh * 2049 + j0 + 2] = i1.x;
            if (t == 0) dst[bh * 2049] = 0.f;
        }
        __syncthreads();   // protect wtot/woff reuse by the next z pass
    }
}

// ---------------------------------------------------------------------------
// K5: per (b,h,i): binary-search k_i, combine prefix sums, write output.
// grid (64 itile, 16 bh), block 256 = 32 i x 8 fg
// ---------------------------------------------------------------------------
__global__ __launch_bounds__(256) void k_out(const float* __restrict__ skey,
                                             const float* __restrict__ e1g,
                                             const float* __restrict__ S1,
                                             const float* __restrict__ P2,
                                             const float* __restrict__ V1,
                                             const float* __restrict__ P2V,
                                             float* __restrict__ out) {
    __shared__ float keys[NTOK];
    const int tid = threadIdx.x;
    const int it  = blockIdx.x;
    const int bh  = blockIdx.y;
    const int b   = bh >> 3;
    const int hh  = bh & 7;
    #pragma unroll
    for (int q = 0; q < 8; ++q)
        keys[q * 256 + tid] = skey[bh * NTOK + q * 256 + tid];
    __syncthreads();

    const int i  = it * 32 + (tid >> 3);
    const int fg = tid & 7;
    const float e1v = e1g[bh * NTOK + i];
    const float th  = -e1v;
    int lo = 0, hi = NTOK;
    while (lo < hi) {
        int mid = (lo + hi) >> 1;
        if (keys[mid] > th) lo = mid + 1; else hi = mid;
    }
    const int k = lo;
    const float A = expf(e1v);
    const float C = expf(0.01f * e1v);
    const float s1  = S1[bh * 2049 + k];
    const float p2k = P2[bh * 2049 + k];
    const float p2t = P2[bh * 2049 + 2048];
    const float l   = A * s1 + C * (p2t - p2k);
    const float inv = 1.0f / l;
    const float* v1p  = V1  + ((size_t)bh * 8 + fg) * (2049u * 4u);
    const float* p2vp = P2V + ((size_t)bh * 8 + fg) * (2049u * 4u);
    float4 v1   = *(const float4*)(v1p  + (size_t)k * 4);
    float4 p2v  = *(const float4*)(p2vp + (size_t)k * 4);
    float4 p2vt = *(const float4*)(p2vp + (size_t)2048 * 4);
    float4 o;
    o.x = (A * v1.x + C * (p2vt.x - p2v.x)) * inv;
    o.y = (A * v1.y + C * (p2vt.y - p2v.y)) * inv;
    o.z = (A * v1.z + C * (p2vt.z - p2v.z)) * inv;
    o.w = (A * v1.w + C * (p2vt.w - p2v.w)) * inv;
    *(float4*)(out + (size_t)(b * NTOK + i) * NCOL + hh * FOUT + fg * 4) = o;
}

// ---------------------------------------------------------------------------
extern "C" void kernel_launch(void* const* d_in, const int* in_sizes, int n_in,
                              void* d_out, int out_size, void* d_ws, size_t ws_size,
                              hipStream_t stream) {
    const float* h = (const float*)d_in[0];
    // d_in[1] = adj — unused by the reference computation
    const float* W = (const float*)d_in[2];
    const float* a = (const float*)d_in[3];
    float* out = (float*)d_out;
    float* ws  = (float*)d_ws;

    float* Wh   = ws;
    float* e1   = ws + OFF_E1;
    float* e2   = ws + OFF_E2;
    float* skey = ws + OFF_SKEY;
    int*   sidx = (int*)(ws + OFF_SIDX);
    float* w1s  = ws + OFF_W1S;
    float* w2s  = ws + OFF_W2S;
    float* S1   = ws + OFF_S1;
    float* P2   = ws + OFF_P2;
    float* V1   = ws + OFF_V1;
    float* P2V  = ws + OFF_P2V;
    int*   part = (int*)(ws + OFF_PART);   // aliases V1 (safe: consumed before vscan)

    k_mm     <<<256,               512, 0, stream>>>(h, W, a, Wh, e1, e2);
    k_rank8  <<<dim3(BH, 8, 2),    256, 0, stream>>>(e2, part);
    k_scatter<<<dim3(BH, 8),       256, 0, stream>>>(e2, part, skey, sidx, w1s, w2s);
    k_vscan  <<<dim3(9, BH),      1024, 0, stream>>>(Wh, sidx, w1s, w2s, V1, P2V, S1, P2);
    k_out    <<<dim3(NTOK/32, BH), 256, 0, stream>>>(skey, e1, S1, P2, V1, P2V, out);
}